// Round 1
// baseline (2120.671 us; speedup 1.0000x reference)
//
#include <hip/hip_runtime.h>

#define NU 60000
#define NI 40000
#define NN 100000
#define NE 1000000
#define NE2 2000000
#define DC 64

__device__ __forceinline__ float wave_sum(float v) {
#pragma unroll
    for (int o = 32; o > 0; o >>= 1) v += __shfl_xor(v, o, 64);
    return v;
}

// ---------------- node init: normalize, build x0 and w = f1n+f2n+f3n ----------------
__global__ __launch_bounds__(256) void k_init(const float* __restrict__ f1,
                                              const float* __restrict__ f2,
                                              const float* __restrict__ f3,
                                              const float* __restrict__ pref,
                                              float* __restrict__ x0,
                                              float* __restrict__ w) {
    int node = (blockIdx.x * blockDim.x + threadIdx.x) >> 6;
    int lane = threadIdx.x & 63;
    if (node >= NN) return;
    if (node < NU) {
        float v = pref[node * DC + lane];
        float n = fmaxf(sqrtf(wave_sum(v * v)), 1e-12f);
        x0[node * DC + lane] = v / n;
    } else {
        int it = node - NU;
        float a = f1[it * DC + lane];
        float b = f2[it * DC + lane];
        float c = f3[it * DC + lane];
        float na = fmaxf(sqrtf(wave_sum(a * a)), 1e-12f);
        float nb = fmaxf(sqrtf(wave_sum(b * b)), 1e-12f);
        float nc = fmaxf(sqrtf(wave_sum(c * c)), 1e-12f);
        float an = a / na;
        x0[node * DC + lane] = an;
        w[it * DC + lane] = an + b / nb + c / nc;
    }
}

// ---------------- CSR build ----------------
__global__ __launch_bounds__(256) void k_count(const int* __restrict__ ei,
                                               int* __restrict__ cnt) {
    int e = blockIdx.x * blockDim.x + threadIdx.x;
    if (e >= NE2) return;
    int dst = (e < NE) ? ei[NE + e] : ei[e - NE];
    atomicAdd(&cnt[dst], 1);
}

__global__ void k_scan(int* __restrict__ cnt, int* __restrict__ off, int n) {
    __shared__ int wsums[16];
    __shared__ int carry;
    int tid = threadIdx.x;
    if (tid == 0) carry = 0;
    __syncthreads();
    int wave = tid >> 6, lane = tid & 63;
    for (int base = 0; base < n; base += 1024) {
        int i = base + tid;
        int v = (i < n) ? cnt[i] : 0;
        int inc = v;
#pragma unroll
        for (int o = 1; o < 64; o <<= 1) {
            int t = __shfl_up(inc, o, 64);
            if (lane >= o) inc += t;
        }
        if (lane == 63) wsums[wave] = inc;
        __syncthreads();
        if (tid == 0) {
            int acc = carry;
#pragma unroll
            for (int k2 = 0; k2 < 16; ++k2) { int t = wsums[k2]; wsums[k2] = acc; acc += t; }
            carry = acc;
        }
        __syncthreads();
        if (i < n) {
            int ex = wsums[wave] + inc - v;
            off[i] = ex;   // exclusive offsets
            cnt[i] = ex;   // cursor copy for fill
        }
        __syncthreads();
    }
    if (tid == 0) off[n] = carry;
}

__global__ __launch_bounds__(256) void k_fill(const int* __restrict__ ei,
                                              int* __restrict__ cur,
                                              int* __restrict__ eid,
                                              int* __restrict__ esrc) {
    int e = blockIdx.x * blockDim.x + threadIdx.x;
    if (e >= NE2) return;
    int src, dst;
    if (e < NE) { src = ei[e];       dst = ei[NE + e]; }
    else        { src = ei[e];       dst = ei[e - NE]; }  // e>=NE: ei[e] == ei[NE + (e-NE)] = item
    int pos = atomicAdd(&cur[dst], 1);
    eid[pos] = e;
    esrc[pos] = src;
}

// ---------------- conv1: multimodal GAT with threshold + re-attention ----------------
__global__ __launch_bounds__(256) void k_conv1(const float* __restrict__ x0,
                                               const float* __restrict__ w,
                                               const int* __restrict__ off,
                                               const int* __restrict__ eid,
                                               const int* __restrict__ esrc,
                                               float* __restrict__ sE,
                                               float* __restrict__ x1,
                                               float* __restrict__ aout) {
    int node = (blockIdx.x * blockDim.x + threadIdx.x) >> 6;
    int lane = threadIdx.x & 63;
    if (node >= NN) return;
    int beg = off[node], end = off[node + 1];
    float xi = x0[node * DC + lane];
    bool user = (node < NU);
    float ai = user ? xi : w[(node - NU) * DC + lane];

    // pass 1: scores (leaky-relu'd), running max; stage s
    float m = -3.4e38f;
    for (int p = beg; p < end; ++p) {
        int s0 = esrc[p];
        const float* gr = user ? (w + (s0 - NU) * DC) : (x0 + s0 * DC);
        float s = wave_sum(ai * gr[lane]) * 0.125f;
        s = (s > 0.f) ? s : 0.2f * s;
        m = fmaxf(m, s);
        if (((p - beg) & 63) == lane) sE[p] = s;
    }
    asm volatile("s_waitcnt vmcnt(0)" ::: "memory");

    // pass 2: exp, den; stage e
    float den = 0.f;
    for (int p = beg; p < end; ++p) {
        float e = expf(sE[p] - m);
        den += e;
        if (((p - beg) & 63) == lane) sE[p] = e;
    }
    asm volatile("s_waitcnt vmcnt(0)" ::: "memory");
    float invden = 1.f / (den + 1e-16f);

    // pass 3: threshold, den2, aggregate; stage t
    float den2 = 0.f, xh = 0.f;
    for (int p = beg; p < end; ++p) {
        float t = sE[p] * invden;
        t = (t > 0.02f) ? t : 0.f;
        den2 += t;
        xh += t * x0[esrc[p] * DC + lane];
        if (((p - beg) & 63) == lane) sE[p] = t;
    }
    asm volatile("s_waitcnt vmcnt(0)" ::: "memory");
    float invden2 = 1.f / (den2 + 1e-16f);

    // pass 4: write re-normalized alpha at original edge ids
    for (int p = beg + lane; p < end; p += 64) {
        aout[eid[p]] = sE[p] * invden2;
    }

    // node update: x = l2norm(x + x_hat)
    float v = xi + xh * invden2;
    float n = fmaxf(sqrtf(wave_sum(v * v)), 1e-12f);
    x1[node * DC + lane] = v / n;
}

// ---------------- routing: plain dot-product GAT ----------------
__global__ __launch_bounds__(256) void k_route(const float* __restrict__ xin,
                                               const int* __restrict__ off,
                                               const int* __restrict__ esrc,
                                               float* __restrict__ xout) {
    int node = (blockIdx.x * blockDim.x + threadIdx.x) >> 6;
    int lane = threadIdx.x & 63;
    if (node >= NN) return;
    int beg = off[node], end = off[node + 1];
    float xi = xin[node * DC + lane];

    float m = -3.4e38f;
    for (int p = beg; p < end; ++p) {
        float g = xin[esrc[p] * DC + lane];
        float s = wave_sum(xi * g) * 0.125f;
        s = (s > 0.f) ? s : 0.2f * s;
        m = fmaxf(m, s);
    }
    float den = 0.f, xh = 0.f;
    for (int p = beg; p < end; ++p) {
        float g = xin[esrc[p] * DC + lane];
        float s = wave_sum(xi * g) * 0.125f;
        s = (s > 0.f) ? s : 0.2f * s;
        float e = expf(s - m);
        den += e;
        xh += e * g;
    }
    float v = xi + xh / (den + 1e-16f);
    float n = fmaxf(sqrtf(wave_sum(v * v)), 1e-12f);
    xout[node * DC + lane] = v / n;
}

extern "C" void kernel_launch(void* const* d_in, const int* in_sizes, int n_in,
                              void* d_out, int out_size, void* d_ws, size_t ws_size,
                              hipStream_t stream) {
    const float* f1   = (const float*)d_in[0];
    const float* f2   = (const float*)d_in[1];
    const float* f3   = (const float*)d_in[2];
    const float* pref = (const float*)d_in[3];
    const int*   ei   = (const int*)d_in[4];

    float* out = (float*)d_out;
    float* x0   = out;                 // ping buffer A (final x lands here)
    float* aout = out + (size_t)NN * DC;

    float* xb  = (float*)d_ws;         // ping buffer B
    float* w   = xb + (size_t)NN * DC;
    float* sE  = w + (size_t)NI * DC;
    int* cnt   = (int*)(sE + NE2);
    int* off   = cnt + NN;
    int* eid   = off + NN + 1;
    int* esrc  = eid + NE2;

    hipMemsetAsync(cnt, 0, NN * sizeof(int), stream);

    k_init<<<(NN * 64) / 256, 256, 0, stream>>>(f1, f2, f3, pref, x0, w);
    k_count<<<(NE2 + 255) / 256, 256, 0, stream>>>(ei, cnt);
    k_scan<<<1, 1024, 0, stream>>>(cnt, off, NN);
    k_fill<<<(NE2 + 255) / 256, 256, 0, stream>>>(ei, cnt, eid, esrc);

    // conv1: x0 -> xb, alpha -> aout
    k_conv1<<<(NN * 64) / 256, 256, 0, stream>>>(x0, w, off, eid, esrc, sE, xb, aout);
    // routing x3: xb -> x0 -> xb -> x0 (final in d_out)
    k_route<<<(NN * 64) / 256, 256, 0, stream>>>(xb, off, esrc, x0);
    k_route<<<(NN * 64) / 256, 256, 0, stream>>>(x0, off, esrc, xb);
    k_route<<<(NN * 64) / 256, 256, 0, stream>>>(xb, off, esrc, x0);
}

// Round 2
// 775.090 us; speedup vs baseline: 2.7360x; 2.7360x over previous
//
#include <hip/hip_runtime.h>

#define NU 60000
#define NI 40000
#define NN 100000
#define NE 1000000
#define NE2 2000000
#define DC 64

// fixed softmax shifts (scores are dots of unit vectors, scaled by 1/8)
#define M_CONV1 0.375f
#define M_ROUTE 0.125f

__device__ __forceinline__ float grp16_sum(float v) {
    v += __shfl_xor(v, 1, 64);
    v += __shfl_xor(v, 2, 64);
    v += __shfl_xor(v, 4, 64);
    v += __shfl_xor(v, 8, 64);
    return v;
}
__device__ __forceinline__ float xgrp_sum(float v) {  // across the 4 groups
    v += __shfl_xor(v, 16, 64);
    v += __shfl_xor(v, 32, 64);
    return v;
}
__device__ __forceinline__ float4 xgrp_sum4(float4 v) {
    v.x = xgrp_sum(v.x); v.y = xgrp_sum(v.y); v.z = xgrp_sum(v.z); v.w = xgrp_sum(v.w);
    return v;
}
__device__ __forceinline__ float dot4(float4 a, float4 b) {
    return a.x * b.x + a.y * b.y + a.z * b.z + a.w * b.w;
}

// ---------------- node init: normalize, build x0 and w = f1n+f2n+f3n ----------------
__global__ __launch_bounds__(256) void k_init(const float* __restrict__ f1,
                                              const float* __restrict__ f2,
                                              const float* __restrict__ f3,
                                              const float* __restrict__ pref,
                                              float* __restrict__ x0,
                                              float* __restrict__ w) {
    int node = (blockIdx.x * blockDim.x + threadIdx.x) >> 6;
    int lane = threadIdx.x & 63;
    if (node >= NN) return;
    if (node < NU) {
        float v = pref[node * DC + lane];
        float s = v * v;
#pragma unroll
        for (int o = 32; o > 0; o >>= 1) s += __shfl_xor(s, o, 64);
        x0[node * DC + lane] = v / fmaxf(sqrtf(s), 1e-12f);
    } else {
        int it = node - NU;
        float a = f1[it * DC + lane];
        float b = f2[it * DC + lane];
        float c = f3[it * DC + lane];
        float sa = a * a, sb = b * b, sc = c * c;
#pragma unroll
        for (int o = 32; o > 0; o >>= 1) {
            sa += __shfl_xor(sa, o, 64);
            sb += __shfl_xor(sb, o, 64);
            sc += __shfl_xor(sc, o, 64);
        }
        float an = a / fmaxf(sqrtf(sa), 1e-12f);
        x0[node * DC + lane] = an;
        w[it * DC + lane] = an + b / fmaxf(sqrtf(sb), 1e-12f) + c / fmaxf(sqrtf(sc), 1e-12f);
    }
}

// ---------------- CSR build ----------------
__global__ __launch_bounds__(256) void k_count(const int* __restrict__ ei,
                                               int* __restrict__ cnt) {
    int e = blockIdx.x * blockDim.x + threadIdx.x;
    if (e >= NE2) return;
    int dst = (e < NE) ? ei[NE + e] : ei[e - NE];
    atomicAdd(&cnt[dst], 1);
}

__global__ void k_scan(int* __restrict__ cnt, int* __restrict__ off, int n) {
    __shared__ int wsums[16];
    __shared__ int carry;
    int tid = threadIdx.x;
    if (tid == 0) carry = 0;
    __syncthreads();
    int wave = tid >> 6, lane = tid & 63;
    for (int base = 0; base < n; base += 1024) {
        int i = base + tid;
        int v = (i < n) ? cnt[i] : 0;
        int inc = v;
#pragma unroll
        for (int o = 1; o < 64; o <<= 1) {
            int t = __shfl_up(inc, o, 64);
            if (lane >= o) inc += t;
        }
        if (lane == 63) wsums[wave] = inc;
        __syncthreads();
        if (tid == 0) {
            int acc = carry;
#pragma unroll
            for (int k2 = 0; k2 < 16; ++k2) { int t = wsums[k2]; wsums[k2] = acc; acc += t; }
            carry = acc;
        }
        __syncthreads();
        if (i < n) {
            int ex = wsums[wave] + inc - v;
            off[i] = ex;
            cnt[i] = ex;
        }
        __syncthreads();
    }
    if (tid == 0) off[n] = carry;
}

__global__ __launch_bounds__(256) void k_fill(const int* __restrict__ ei,
                                              int* __restrict__ cur,
                                              int* __restrict__ eid,
                                              int* __restrict__ esrc) {
    int e = blockIdx.x * blockDim.x + threadIdx.x;
    if (e >= NE2) return;
    int src = ei[e];
    int dst = (e < NE) ? ei[NE + e] : ei[e - NE];
    int pos = atomicAdd(&cur[dst], 1);
    eid[pos] = e;
    esrc[pos] = src;
}

// ---------------- conv1: multimodal GAT with threshold + re-attention ----------------
// 4 edges per wave iteration, 16 lanes (float4) per edge
__global__ __launch_bounds__(256) void k_conv1(const float* __restrict__ x0,
                                               const float* __restrict__ w,
                                               const int* __restrict__ off,
                                               const int* __restrict__ eid,
                                               const int* __restrict__ esrc,
                                               float* __restrict__ sE,
                                               float* __restrict__ x1,
                                               float* __restrict__ aout) {
    int node = (blockIdx.x * blockDim.x + threadIdx.x) >> 6;
    int lane = threadIdx.x & 63;
    if (node >= NN) return;
    int grp = lane >> 4, gl = lane & 15;
    int beg = off[node], end = off[node + 1];
    bool user = (node < NU);

    float4 xi4 = *((const float4*)(x0 + (size_t)node * DC) + gl);
    float4 ai4 = user ? xi4 : *((const float4*)(w + (size_t)(node - NU) * DC) + gl);
    const float* gbase = user ? w : x0;   // gather table for scores
    int goff = user ? NU : 0;             // subtract from src for w indexing

    // pass A: scores -> e = exp(lrelu(s) - M); den; stage e
    float den = 0.f;
    for (int p0 = beg; p0 < end; p0 += 4) {
        int p = p0 + grp;
        bool act = p < end;
        int s0 = act ? (esrc[p] - goff) : 0;
        float4 g4 = *((const float4*)(gbase + (size_t)s0 * DC) + gl);
        float s = grp16_sum(dot4(ai4, g4)) * 0.125f;
        s = (s > 0.f) ? s : 0.2f * s;
        float e = act ? __expf(s - M_CONV1) : 0.f;
        den += e;
        if (act && gl == 0) sE[p] = e;
    }
    den = xgrp_sum(den);
    float invden = 1.f / (den + 1e-16f);
    asm volatile("s_waitcnt vmcnt(0)" ::: "memory");

    // pass B: threshold, den2, aggregate x0[src]
    float den2 = 0.f;
    float4 xh4 = {0.f, 0.f, 0.f, 0.f};
    for (int p0 = beg; p0 < end; p0 += 4) {
        int p = p0 + grp;
        bool act = p < end;
        int s0 = act ? esrc[p] : 0;
        float e = act ? sE[p] : 0.f;
        float a = e * invden;
        float t = (a > 0.02f) ? a : 0.f;
        den2 += t;
        float4 g4 = *((const float4*)(x0 + (size_t)s0 * DC) + gl);
        xh4.x += t * g4.x; xh4.y += t * g4.y; xh4.z += t * g4.z; xh4.w += t * g4.w;
    }
    den2 = xgrp_sum(den2);
    xh4 = xgrp_sum4(xh4);
    float invden2 = 1.f / (den2 + 1e-16f);

    // pass C: write re-normalized alpha at original edge ids (scalar, 64 lanes)
    for (int p = beg + lane; p < end; p += 64) {
        float a = sE[p] * invden;
        float t = (a > 0.02f) ? a : 0.f;
        aout[eid[p]] = t * invden2;
    }

    // node update: x = l2norm(x + x_hat)
    float4 v;
    v.x = xi4.x + xh4.x * invden2;
    v.y = xi4.y + xh4.y * invden2;
    v.z = xi4.z + xh4.z * invden2;
    v.w = xi4.w + xh4.w * invden2;
    float nn = grp16_sum(dot4(v, v));
    float inv_n = 1.f / fmaxf(sqrtf(nn), 1e-12f);
    if (grp == 0) {
        float4 o = {v.x * inv_n, v.y * inv_n, v.z * inv_n, v.w * inv_n};
        *((float4*)(x1 + (size_t)node * DC) + gl) = o;
    }
}

// ---------------- routing: plain dot-product GAT, single gather pass ----------------
__global__ __launch_bounds__(256) void k_route(const float* __restrict__ xin,
                                               const int* __restrict__ off,
                                               const int* __restrict__ esrc,
                                               float* __restrict__ xout) {
    int node = (blockIdx.x * blockDim.x + threadIdx.x) >> 6;
    int lane = threadIdx.x & 63;
    if (node >= NN) return;
    int grp = lane >> 4, gl = lane & 15;
    int beg = off[node], end = off[node + 1];

    float4 xi4 = *((const float4*)(xin + (size_t)node * DC) + gl);

    float den = 0.f;
    float4 xh4 = {0.f, 0.f, 0.f, 0.f};
    for (int p0 = beg; p0 < end; p0 += 4) {
        int p = p0 + grp;
        bool act = p < end;
        int s0 = act ? esrc[p] : 0;
        float4 g4 = *((const float4*)(xin + (size_t)s0 * DC) + gl);
        float s = grp16_sum(dot4(xi4, g4)) * 0.125f;
        s = (s > 0.f) ? s : 0.2f * s;
        float e = act ? __expf(s - M_ROUTE) : 0.f;
        den += e;
        xh4.x += e * g4.x; xh4.y += e * g4.y; xh4.z += e * g4.z; xh4.w += e * g4.w;
    }
    den = xgrp_sum(den);
    xh4 = xgrp_sum4(xh4);
    float inv = 1.f / (den + 1e-16f);

    float4 v;
    v.x = xi4.x + xh4.x * inv;
    v.y = xi4.y + xh4.y * inv;
    v.z = xi4.z + xh4.z * inv;
    v.w = xi4.w + xh4.w * inv;
    float nn = grp16_sum(dot4(v, v));
    float inv_n = 1.f / fmaxf(sqrtf(nn), 1e-12f);
    if (grp == 0) {
        float4 o = {v.x * inv_n, v.y * inv_n, v.z * inv_n, v.w * inv_n};
        *((float4*)(xout + (size_t)node * DC) + gl) = o;
    }
}

extern "C" void kernel_launch(void* const* d_in, const int* in_sizes, int n_in,
                              void* d_out, int out_size, void* d_ws, size_t ws_size,
                              hipStream_t stream) {
    const float* f1   = (const float*)d_in[0];
    const float* f2   = (const float*)d_in[1];
    const float* f3   = (const float*)d_in[2];
    const float* pref = (const float*)d_in[3];
    const int*   ei   = (const int*)d_in[4];

    float* out = (float*)d_out;
    float* x0   = out;                 // ping buffer A (final x lands here)
    float* aout = out + (size_t)NN * DC;

    float* xb  = (float*)d_ws;         // ping buffer B
    float* w   = xb + (size_t)NN * DC;
    float* sE  = w + (size_t)NI * DC;
    int* cnt   = (int*)(sE + NE2);
    int* off   = cnt + NN;
    int* eid   = off + NN + 1;
    int* esrc  = eid + NE2;

    hipMemsetAsync(cnt, 0, NN * sizeof(int), stream);

    k_init<<<(NN * 64) / 256, 256, 0, stream>>>(f1, f2, f3, pref, x0, w);
    k_count<<<(NE2 + 255) / 256, 256, 0, stream>>>(ei, cnt);
    k_scan<<<1, 1024, 0, stream>>>(cnt, off, NN);
    k_fill<<<(NE2 + 255) / 256, 256, 0, stream>>>(ei, cnt, eid, esrc);

    // conv1: x0 -> xb, alpha -> aout
    k_conv1<<<(NN * 64) / 256, 256, 0, stream>>>(x0, w, off, eid, esrc, sE, xb, aout);
    // routing x3: xb -> x0 -> xb -> x0 (final in d_out)
    k_route<<<(NN * 64) / 256, 256, 0, stream>>>(xb, off, esrc, x0);
    k_route<<<(NN * 64) / 256, 256, 0, stream>>>(x0, off, esrc, xb);
    k_route<<<(NN * 64) / 256, 256, 0, stream>>>(xb, off, esrc, x0);
}

// Round 3
// 635.994 us; speedup vs baseline: 3.3344x; 1.2187x over previous
//
#include <hip/hip_runtime.h>

#define NU 60000
#define NI 40000
#define NN 100000
#define NE 1000000
#define NE2 2000000
#define DC 64

// fixed softmax shifts (scores are dots of unit vectors, scaled by 1/8)
#define M_CONV1 0.375f
#define M_ROUTE 0.125f

typedef unsigned short u16;

__device__ __forceinline__ float grp16_sum(float v) {
    v += __shfl_xor(v, 1, 64);
    v += __shfl_xor(v, 2, 64);
    v += __shfl_xor(v, 4, 64);
    v += __shfl_xor(v, 8, 64);
    return v;
}
__device__ __forceinline__ float xgrp_sum(float v) {  // across the 4 groups
    v += __shfl_xor(v, 16, 64);
    v += __shfl_xor(v, 32, 64);
    return v;
}
__device__ __forceinline__ float4 xgrp_sum4(float4 v) {
    v.x = xgrp_sum(v.x); v.y = xgrp_sum(v.y); v.z = xgrp_sum(v.z); v.w = xgrp_sum(v.w);
    return v;
}
__device__ __forceinline__ float dot4(float4 a, float4 b) {
    return a.x * b.x + a.y * b.y + a.z * b.z + a.w * b.w;
}
__device__ __forceinline__ u16 f2b(float f) {
    union { float f; unsigned u; } a; a.f = f;
    unsigned r = a.u + 0x7FFFu + ((a.u >> 16) & 1u);
    return (u16)(r >> 16);
}
__device__ __forceinline__ float b2f(u16 b) {
    union { unsigned u; float f; } a; a.u = ((unsigned)b) << 16;
    return a.f;
}
__device__ __forceinline__ float4 b2f4(ushort4 h) {
    float4 f; f.x = b2f(h.x); f.y = b2f(h.y); f.z = b2f(h.z); f.w = b2f(h.w);
    return f;
}

// ---------------- node init: normalize, build x0(f32+bf16) and w = f1n+f2n+f3n ----------------
__global__ __launch_bounds__(256) void k_init(const float* __restrict__ f1,
                                              const float* __restrict__ f2,
                                              const float* __restrict__ f3,
                                              const float* __restrict__ pref,
                                              float* __restrict__ x0,
                                              u16* __restrict__ x016,
                                              float* __restrict__ w) {
    int node = (blockIdx.x * blockDim.x + threadIdx.x) >> 6;
    int lane = threadIdx.x & 63;
    if (node >= NN) return;
    float outv;
    if (node < NU) {
        float v = pref[node * DC + lane];
        float s = v * v;
#pragma unroll
        for (int o = 32; o > 0; o >>= 1) s += __shfl_xor(s, o, 64);
        outv = v / fmaxf(sqrtf(s), 1e-12f);
    } else {
        int it = node - NU;
        float a = f1[it * DC + lane];
        float b = f2[it * DC + lane];
        float c = f3[it * DC + lane];
        float sa = a * a, sb = b * b, sc = c * c;
#pragma unroll
        for (int o = 32; o > 0; o >>= 1) {
            sa += __shfl_xor(sa, o, 64);
            sb += __shfl_xor(sb, o, 64);
            sc += __shfl_xor(sc, o, 64);
        }
        outv = a / fmaxf(sqrtf(sa), 1e-12f);
        w[it * DC + lane] = outv + b / fmaxf(sqrtf(sb), 1e-12f) + c / fmaxf(sqrtf(sc), 1e-12f);
    }
    x0[node * DC + lane] = outv;
    x016[node * DC + lane] = f2b(outv);
}

// ---------------- CSR build ----------------
__global__ __launch_bounds__(256) void k_count(const int* __restrict__ ei,
                                               int* __restrict__ cnt) {
    int e = blockIdx.x * blockDim.x + threadIdx.x;
    if (e >= NE2) return;
    int dst = (e < NE) ? ei[NE + e] : ei[e - NE];
    atomicAdd(&cnt[dst], 1);
}

__device__ __forceinline__ int block_exscan1024(int v) {
    __shared__ int wsum[16];
    int tid = threadIdx.x, lane = tid & 63;
    int wv = tid >> 6;
    int inc = v;
#pragma unroll
    for (int o = 1; o < 64; o <<= 1) {
        int t = __shfl_up(inc, o, 64);
        if (lane >= o) inc += t;
    }
    if (lane == 63) wsum[wv] = inc;
    __syncthreads();
    if (tid < 16) {
        int b = wsum[tid];
        int binc = b;
#pragma unroll
        for (int o = 1; o < 16; o <<= 1) {
            int t = __shfl_up(binc, o, 16);
            if (tid >= o) binc += t;
        }
        wsum[tid] = binc - b;  // exclusive wave prefix
    }
    __syncthreads();
    return wsum[wv] + inc - v;
}

__global__ __launch_bounds__(1024) void k_scan1(const int* __restrict__ cnt,
                                                int* __restrict__ off,
                                                int* __restrict__ bsum) {
    int i = blockIdx.x * 1024 + threadIdx.x;
    int v = (i < NN) ? cnt[i] : 0;
    int ex = block_exscan1024(v);
    if (i < NN) off[i] = ex;
    if (threadIdx.x == 1023) bsum[blockIdx.x] = ex + v;
}

__global__ __launch_bounds__(1024) void k_scan2(int* __restrict__ bsum, int nb) {
    int v = (threadIdx.x < nb) ? bsum[threadIdx.x] : 0;
    int ex = block_exscan1024(v);
    if (threadIdx.x < nb) bsum[threadIdx.x] = ex;
}

__global__ __launch_bounds__(1024) void k_scan3(int* __restrict__ off,
                                                const int* __restrict__ bsum,
                                                int* __restrict__ cur) {
    int i = blockIdx.x * 1024 + threadIdx.x;
    if (i < NN) {
        int o = off[i] + bsum[blockIdx.x];
        off[i] = o;
        cur[i] = o;
    }
    if (i == 0) off[NN] = NE2;
}

__global__ __launch_bounds__(256) void k_fill(const int* __restrict__ ei,
                                              int* __restrict__ cur,
                                              int* __restrict__ eid,
                                              int* __restrict__ esrc) {
    int e = blockIdx.x * blockDim.x + threadIdx.x;
    if (e >= NE2) return;
    int src = ei[e];
    int dst = (e < NE) ? ei[NE + e] : ei[e - NE];
    int pos = atomicAdd(&cur[dst], 1);
    eid[pos] = e;
    esrc[pos] = src;
}

// ---------------- conv1: multimodal GAT with threshold + re-attention ----------------
// 8 edges per wave iteration (2 per 16-lane group), float4 per edge-lane
__global__ __launch_bounds__(256) void k_conv1(const float* __restrict__ x0,
                                               const float* __restrict__ w,
                                               const u16* __restrict__ x16,
                                               const int* __restrict__ off,
                                               const int* __restrict__ eid,
                                               const int* __restrict__ esrc,
                                               float* __restrict__ sE,
                                               float* __restrict__ x1,
                                               u16* __restrict__ x116,
                                               float* __restrict__ aout) {
    int node = (blockIdx.x * blockDim.x + threadIdx.x) >> 6;
    int lane = threadIdx.x & 63;
    if (node >= NN) return;
    int grp = lane >> 4, gl = lane & 15;
    int beg = off[node], end = off[node + 1];
    bool user = (node < NU);

    float4 xi4 = *((const float4*)(x0 + (size_t)node * DC) + gl);
    float4 ai4 = user ? xi4 : *((const float4*)(w + (size_t)(node - NU) * DC) + gl);
    const float* gbase = user ? w : x0;
    int goff = user ? NU : 0;

    // pass A: f32 scores -> e = exp(lrelu(s) - M); den; stage e
    float den = 0.f;
    for (int p0 = beg; p0 < end; p0 += 8) {
        int pA = p0 + grp, pB = p0 + 4 + grp;
        bool aA = pA < end, aB = pB < end;
        int sA = aA ? (esrc[pA] - goff) : 0;
        int sB = aB ? (esrc[pB] - goff) : 0;
        float4 gA = *((const float4*)(gbase + (size_t)sA * DC) + gl);
        float4 gB = *((const float4*)(gbase + (size_t)sB * DC) + gl);
        float dA = grp16_sum(dot4(ai4, gA)) * 0.125f;
        float dB = grp16_sum(dot4(ai4, gB)) * 0.125f;
        dA = (dA > 0.f) ? dA : 0.2f * dA;
        dB = (dB > 0.f) ? dB : 0.2f * dB;
        float eA = aA ? __expf(dA - M_CONV1) : 0.f;
        float eB = aB ? __expf(dB - M_CONV1) : 0.f;
        den += eA + eB;
        if (aA && gl == 0) sE[pA] = eA;
        if (aB && gl == 0) sE[pB] = eB;
    }
    den = xgrp_sum(den);
    float invden = 1.f / (den + 1e-16f);
    asm volatile("s_waitcnt vmcnt(0)" ::: "memory");

    // pass B: threshold, den2, aggregate bf16 x[src]
    float den2 = 0.f;
    float4 xh = {0.f, 0.f, 0.f, 0.f};
    for (int p0 = beg; p0 < end; p0 += 8) {
        int pA = p0 + grp, pB = p0 + 4 + grp;
        bool aA = pA < end, aB = pB < end;
        int sA = aA ? esrc[pA] : 0;
        int sB = aB ? esrc[pB] : 0;
        ushort4 hA = *((const ushort4*)(x16 + (size_t)sA * DC) + gl);
        ushort4 hB = *((const ushort4*)(x16 + (size_t)sB * DC) + gl);
        float eA = aA ? sE[pA] : 0.f;
        float eB = aB ? sE[pB] : 0.f;
        float aAv = eA * invden, aBv = eB * invden;
        float tA = (aAv > 0.02f) ? aAv : 0.f;
        float tB = (aBv > 0.02f) ? aBv : 0.f;
        den2 += tA + tB;
        float4 fA = b2f4(hA);
        float4 fB = b2f4(hB);
        xh.x += tA * fA.x + tB * fB.x;
        xh.y += tA * fA.y + tB * fB.y;
        xh.z += tA * fA.z + tB * fB.z;
        xh.w += tA * fA.w + tB * fB.w;
    }
    den2 = xgrp_sum(den2);
    xh = xgrp_sum4(xh);
    float invden2 = 1.f / (den2 + 1e-16f);

    // pass C: write re-normalized alpha at original edge ids
    for (int p = beg + lane; p < end; p += 64) {
        float a = sE[p] * invden;
        float t = (a > 0.02f) ? a : 0.f;
        aout[eid[p]] = t * invden2;
    }

    // node update: x = l2norm(x + x_hat)
    float4 v;
    v.x = xi4.x + xh.x * invden2;
    v.y = xi4.y + xh.y * invden2;
    v.z = xi4.z + xh.z * invden2;
    v.w = xi4.w + xh.w * invden2;
    float nn = grp16_sum(dot4(v, v));
    float inv_n = 1.f / fmaxf(sqrtf(nn), 1e-12f);
    if (grp == 0) {
        float4 o = {v.x * inv_n, v.y * inv_n, v.z * inv_n, v.w * inv_n};
        *((float4*)(x1 + (size_t)node * DC) + gl) = o;
        ushort4 h = {f2b(o.x), f2b(o.y), f2b(o.z), f2b(o.w)};
        *((ushort4*)(x116 + (size_t)node * DC) + gl) = h;
    }
}

// ---------------- routing: plain dot-product GAT, single pass, bf16 gathers ----------------
__global__ __launch_bounds__(256) void k_route(const float* __restrict__ xin,
                                               const u16* __restrict__ g16,
                                               const int* __restrict__ off,
                                               const int* __restrict__ esrc,
                                               float* __restrict__ xout,
                                               u16* __restrict__ out16) {
    int node = (blockIdx.x * blockDim.x + threadIdx.x) >> 6;
    int lane = threadIdx.x & 63;
    if (node >= NN) return;
    int grp = lane >> 4, gl = lane & 15;
    int beg = off[node], end = off[node + 1];

    float4 xi4 = *((const float4*)(xin + (size_t)node * DC) + gl);

    float den = 0.f;
    float4 xh = {0.f, 0.f, 0.f, 0.f};
    for (int p0 = beg; p0 < end; p0 += 8) {
        int pA = p0 + grp, pB = p0 + 4 + grp;
        bool aA = pA < end, aB = pB < end;
        int sA = aA ? esrc[pA] : 0;
        int sB = aB ? esrc[pB] : 0;
        ushort4 hA = *((const ushort4*)(g16 + (size_t)sA * DC) + gl);
        ushort4 hB = *((const ushort4*)(g16 + (size_t)sB * DC) + gl);
        float4 fA = b2f4(hA);
        float4 fB = b2f4(hB);
        float dA = grp16_sum(dot4(xi4, fA)) * 0.125f;
        float dB = grp16_sum(dot4(xi4, fB)) * 0.125f;
        dA = (dA > 0.f) ? dA : 0.2f * dA;
        dB = (dB > 0.f) ? dB : 0.2f * dB;
        float eA = aA ? __expf(dA - M_ROUTE) : 0.f;
        float eB = aB ? __expf(dB - M_ROUTE) : 0.f;
        den += eA + eB;
        xh.x += eA * fA.x + eB * fB.x;
        xh.y += eA * fA.y + eB * fB.y;
        xh.z += eA * fA.z + eB * fB.z;
        xh.w += eA * fA.w + eB * fB.w;
    }
    den = xgrp_sum(den);
    xh = xgrp_sum4(xh);
    float inv = 1.f / (den + 1e-16f);

    float4 v;
    v.x = xi4.x + xh.x * inv;
    v.y = xi4.y + xh.y * inv;
    v.z = xi4.z + xh.z * inv;
    v.w = xi4.w + xh.w * inv;
    float nn = grp16_sum(dot4(v, v));
    float inv_n = 1.f / fmaxf(sqrtf(nn), 1e-12f);
    if (grp == 0) {
        float4 o = {v.x * inv_n, v.y * inv_n, v.z * inv_n, v.w * inv_n};
        *((float4*)(xout + (size_t)node * DC) + gl) = o;
        ushort4 h = {f2b(o.x), f2b(o.y), f2b(o.z), f2b(o.w)};
        *((ushort4*)(out16 + (size_t)node * DC) + gl) = h;
    }
}

extern "C" void kernel_launch(void* const* d_in, const int* in_sizes, int n_in,
                              void* d_out, int out_size, void* d_ws, size_t ws_size,
                              hipStream_t stream) {
    const float* f1   = (const float*)d_in[0];
    const float* f2   = (const float*)d_in[1];
    const float* f3   = (const float*)d_in[2];
    const float* pref = (const float*)d_in[3];
    const int*   ei   = (const int*)d_in[4];

    float* out  = (float*)d_out;
    float* x0   = out;                       // ping buffer A (final x lands here)
    float* aout = out + (size_t)NN * DC;

    float* xb   = (float*)d_ws;              // ping buffer B (f32)
    float* w    = xb + (size_t)NN * DC;
    float* sE   = w + (size_t)NI * DC;
    u16*  xa16  = (u16*)(sE + NE2);          // bf16 ping A
    u16*  xb16  = xa16 + (size_t)NN * DC;    // bf16 ping B
    int* cnt    = (int*)(xb16 + (size_t)NN * DC);
    int* off    = cnt + NN;
    int* bsum   = off + NN + 1;
    int* eid    = bsum + 1024;
    int* esrc   = eid + NE2;

    hipMemsetAsync(cnt, 0, NN * sizeof(int), stream);

    int nb = (NN + 1023) / 1024;
    k_init<<<(NN * 64) / 256, 256, 0, stream>>>(f1, f2, f3, pref, x0, xa16, w);
    k_count<<<(NE2 + 255) / 256, 256, 0, stream>>>(ei, cnt);
    k_scan1<<<nb, 1024, 0, stream>>>(cnt, off, bsum);
    k_scan2<<<1, 1024, 0, stream>>>(bsum, nb);
    k_scan3<<<nb, 1024, 0, stream>>>(off, bsum, cnt);
    k_fill<<<(NE2 + 255) / 256, 256, 0, stream>>>(ei, cnt, eid, esrc);

    // conv1: x0 -> xb (+xb16), alpha -> aout  (scores f32, aggregation bf16)
    k_conv1<<<(NN * 64) / 256, 256, 0, stream>>>(x0, w, xa16, off, eid, esrc, sE, xb, xb16, aout);
    // routing x3: xb -> x0 -> xb -> x0 (final in d_out)
    k_route<<<(NN * 64) / 256, 256, 0, stream>>>(xb, xb16, off, esrc, x0, xa16);
    k_route<<<(NN * 64) / 256, 256, 0, stream>>>(x0, xa16, off, esrc, xb, xb16);
    k_route<<<(NN * 64) / 256, 256, 0, stream>>>(xb, xb16, off, esrc, x0, xa16);
}